// Round 2
// baseline (4593.570 us; speedup 1.0000x reference)
//
#include <hip/hip_runtime.h>
#include <hip/hip_bf16.h>

#define DIM     128
#define NVARS   12000
#define NNODES  8400
#define NLEAF   (NVARS - NNODES)   // 3600
#define NROUNDS 12
#define NODE_CAP 96
#define VAR_CAP  96

#define FLAG_RELU  1
#define FLAG_ACCUM 2

// ---------------------------------------------------------------------------
// Build CSR (node rows -> var indices) and CSC-as-CSR (var rows -> node
// indices) from the 0/1 fp32 incidence matrix. Order within a row is
// nondeterministic (atomics) but fp32 sums of ~10 terms are fine at 2% tol.
// ---------------------------------------------------------------------------
__global__ void build_csr(const unsigned int* __restrict__ up,   // fp32 bits
                          int* __restrict__ ncnt, int* __restrict__ nidx,
                          int* __restrict__ vcnt, int* __restrict__ vidx) {
    const int total4 = NNODES * (NVARS / 4);        // float4 groups, row-aligned
    const uint4* up4 = (const uint4*)up;
    for (int p = blockIdx.x * blockDim.x + threadIdx.x;
         p < total4; p += gridDim.x * blockDim.x) {
        uint4 w = up4[p];
        if ((w.x | w.y | w.z | w.w) == 0u) continue;
        int n  = p / (NVARS / 4);
        int v0 = (p % (NVARS / 4)) * 4;
        unsigned e[4] = { w.x, w.y, w.z, w.w };
#pragma unroll
        for (int j = 0; j < 4; j++) {
            if (e[j]) {                              // 1.0f (nonzero bits)
                int v = v0 + j;
                int s1 = atomicAdd(&ncnt[n], 1);
                if (s1 < NODE_CAP) nidx[n * NODE_CAP + s1] = v;
                int s2 = atomicAdd(&vcnt[v], 1);
                if (s2 < VAR_CAP) vidx[v * VAR_CAP + s2] = n;
            }
        }
    }
}

// ---------------------------------------------------------------------------
// h0[v,:] = vt[v]==1 ? true_w+true_b : false_w+false_b ; c0 = 0
// ---------------------------------------------------------------------------
__global__ void init_hc(const int* __restrict__ vt,
                        const float* __restrict__ tw, const float* __restrict__ tb,
                        const float* __restrict__ fw, const float* __restrict__ fb,
                        float* __restrict__ h, float* __restrict__ c) {
    int t = blockIdx.x * blockDim.x + threadIdx.x;
    if (t >= NVARS * DIM) return;
    int v = t >> 7, d = t & 127;
    float val = (vt[v] == 1) ? (tw[d] + tb[d]) : (fw[d] + fb[d]);
    h[t] = val;
    c[t] = 0.f;
}

// ---------------------------------------------------------------------------
// C[M,N] = A[M,128] * B[N,128]^T  (+ C if ACCUM) (+ bias[n]) (ReLU optional)
// 64x64 tile, 256 threads, 4x4 per thread, K staged 16 at a time.
// ---------------------------------------------------------------------------
__global__ void gemm_abt(const float* __restrict__ A, const float* __restrict__ B,
                         const float* __restrict__ bias, float* __restrict__ C,
                         int M, int N, int flags) {
    const int tid = threadIdx.x;
    const int tx = tid & 15, ty = tid >> 4;
    const int rowBase = blockIdx.y * 64, colBase = blockIdx.x * 64;
    __shared__ float As[16][65];
    __shared__ float Bs[16][65];
    float acc[4][4] = {};
    for (int kk = 0; kk < DIM; kk += 16) {
#pragma unroll
        for (int i = 0; i < 4; i++) {
            int idx = tid + i * 256;          // 0..1023
            int m = idx >> 4, k = idx & 15;
            int row = rowBase + m;
            As[k][m] = (row < M) ? A[row * DIM + kk + k] : 0.f;
            int col = colBase + m;            // N is a multiple of 64
            Bs[k][m] = B[col * DIM + kk + k];
        }
        __syncthreads();
#pragma unroll
        for (int k = 0; k < 16; k++) {
            float a[4], b[4];
#pragma unroll
            for (int i = 0; i < 4; i++) a[i] = As[k][ty * 4 + i];
#pragma unroll
            for (int j = 0; j < 4; j++) b[j] = Bs[k][tx * 4 + j];
#pragma unroll
            for (int i = 0; i < 4; i++)
#pragma unroll
                for (int j = 0; j < 4; j++)
                    acc[i][j] = fmaf(a[i], b[j], acc[i][j]);
        }
        __syncthreads();
    }
#pragma unroll
    for (int i = 0; i < 4; i++) {
        int row = rowBase + ty * 4 + i;
        if (row >= M) continue;
#pragma unroll
        for (int j = 0; j < 4; j++) {
            int col = colBase + tx * 4 + j;
            float v = acc[i][j];
            if (flags & FLAG_ACCUM) v += C[row * N + col];
            if (bias) v += bias[col];
            if (flags & FLAG_RELU) v = fmaxf(v, 0.f);
            C[row * N + col] = v;
        }
    }
}

// ---------------------------------------------------------------------------
// dst[r,:] = sum_{j<cnt[r]} src[idx[r,j],:]    (sparse 0/1 incidence matmul)
// One block (128 threads) per row; loads coalesced across dims.
// ---------------------------------------------------------------------------
__global__ void gather_rows(const float* __restrict__ src, const int* __restrict__ idx,
                            const int* __restrict__ cnt, int cap,
                            float* __restrict__ dst) {
    int r = blockIdx.x, d = threadIdx.x;
    int n = cnt[r];
    if (n > cap) n = cap;
    const int* ir = idx + r * cap;
    float s = 0.f;
    for (int j = 0; j < n; j++) s += src[ir[j] * DIM + d];
    dst[r * DIM + d] = s;
}

// ---------------------------------------------------------------------------
// LSTM pointwise: gates[r, 0:512] in PyTorch order (i,f,g,o); adds bih+bhh.
// ---------------------------------------------------------------------------
__device__ __forceinline__ float sigm(float x) { return 1.f / (1.f + expf(-x)); }

__global__ void lstm_pw(const float* __restrict__ g,
                        const float* __restrict__ bih, const float* __restrict__ bhh,
                        float* __restrict__ h, float* __restrict__ c, int rows) {
    int t = blockIdx.x * blockDim.x + threadIdx.x;
    if (t >= rows * DIM) return;
    int r = t >> 7, d = t & 127;
    const float* gr = g + r * 512;
    float gi = gr[d]       + bih[d]       + bhh[d];
    float gf = gr[128 + d] + bih[128 + d] + bhh[128 + d];
    float gg = gr[256 + d] + bih[256 + d] + bhh[256 + d];
    float go = gr[384 + d] + bih[384 + d] + bhh[384 + d];
    float c2 = sigm(gf) * c[t] + sigm(gi) * tanhf(gg);
    float h2 = sigm(go) * tanhf(c2);
    c[t] = c2;
    h[t] = h2;
}

// ---------------------------------------------------------------------------
// Final vote layer: out[r] = x[r,:] . w3[0,:] + b3   (fp32 out)
// ---------------------------------------------------------------------------
__global__ void vote_out(const float* __restrict__ x, const float* __restrict__ w3,
                         const float* __restrict__ b3, float* __restrict__ out) {
    int r = blockIdx.x * blockDim.x + threadIdx.x;
    if (r >= NLEAF) return;
    float s = b3[0];
    for (int k = 0; k < DIM; k++) s += x[r * DIM + k] * w3[k];
    out[r] = s;
}

// ---------------------------------------------------------------------------
static inline void launch_gemm(const float* A, const void* B, const void* bias, float* C,
                               int M, int N, int flags, hipStream_t s) {
    dim3 grid(N / 64, (M + 63) / 64);
    gemm_abt<<<grid, 256, 0, s>>>(A, (const float*)B, (const float*)bias, C, M, N, flags);
}

extern "C" void kernel_launch(void* const* d_in, const int* in_sizes, int n_in,
                              void* d_out, int out_size, void* d_ws, size_t ws_size,
                              hipStream_t stream) {
    // --- input pointers (setup_inputs dict order, all floats fp32) ---
    const int* vt                = (const int*)d_in[0];
    const unsigned int* unpack   = (const unsigned int*)d_in[1];   // fp32 bits
    const float* true_w          = (const float*)d_in[2];
    const float* true_b          = (const float*)d_in[3];
    const float* false_w         = (const float*)d_in[4];
    const float* false_b         = (const float*)d_in[5];
    const void *cm_w1 = d_in[6],  *cm_b1 = d_in[7],  *cm_w2 = d_in[8],  *cm_b2 = d_in[9],
               *cm_w3 = d_in[10], *cm_b3 = d_in[11];
    const void *pm_w1 = d_in[12], *pm_b1 = d_in[13], *pm_w2 = d_in[14], *pm_b2 = d_in[15],
               *pm_w3 = d_in[16], *pm_b3 = d_in[17];
    const void *vv_w1 = d_in[18], *vv_b1 = d_in[19], *vv_w2 = d_in[20], *vv_b2 = d_in[21],
               *vv_w3 = d_in[22], *vv_b3 = d_in[23];
    const void *vu_wih = d_in[24], *vu_whh = d_in[25], *vu_bih = d_in[26], *vu_bhh = d_in[27];
    const void *nu_wih = d_in[28], *nu_whh = d_in[29], *nu_bih = d_in[30], *nu_bhh = d_in[31];

    // --- workspace layout (fp32 activations + CSR) ---
    float* h     = (float*)d_ws;            // [NVARS,128]
    float* c     = h   + NVARS * DIM;       // [NVARS,128]
    float* t1    = c   + NVARS * DIM;       // [NVARS,128]
    float* t2    = t1  + NVARS * DIM;       // [NVARS,128]
    float* msg   = t2  + NVARS * DIM;       // [NVARS,128]
    float* gates = msg + NVARS * DIM;       // [NVARS,512]
    int* ncnt = (int*)(gates + NVARS * 512);
    int* nidx = ncnt + NNODES;              // [NNODES, NODE_CAP]
    int* vcnt = nidx + NNODES * NODE_CAP;
    int* vidx = vcnt + NVARS;               // [NVARS, VAR_CAP]

    // --- per-call setup: CSR of the incidence matrix + h0/c0 ---
    hipMemsetAsync(ncnt, 0, NNODES * sizeof(int), stream);
    hipMemsetAsync(vcnt, 0, NVARS * sizeof(int), stream);
    build_csr<<<4096, 256, 0, stream>>>(unpack, ncnt, nidx, vcnt, vidx);
    init_hc<<<(NVARS * DIM + 255) / 256, 256, 0, stream>>>(vt, true_w, true_b, false_w, false_b, h, c);

    for (int round = 0; round < NROUNDS; round++) {
        // msg = unpack @ mlp_cm(h)   (mlp over ALL vars)
        launch_gemm(h,  cm_w1, cm_b1, t1, NVARS, DIM, FLAG_RELU, stream);
        launch_gemm(t1, cm_w2, cm_b2, t2, NVARS, DIM, FLAG_RELU, stream);
        launch_gemm(t2, cm_w3, cm_b3, t1, NVARS, DIM, 0, stream);
        gather_rows<<<NNODES, DIM, 0, stream>>>(t1, nidx, ncnt, NODE_CAP, msg);

        // (h,c)[:8400] = LSTM_vu(msg, h[:8400], c[:8400])
        launch_gemm(msg, vu_wih, nullptr, gates, NNODES, 512, 0, stream);
        launch_gemm(h,   vu_whh, nullptr, gates, NNODES, 512, FLAG_ACCUM, stream);
        lstm_pw<<<(NNODES * DIM + 255) / 256, 256, 0, stream>>>(
            gates, (const float*)vu_bih, (const float*)vu_bhh, h, c, NNODES);

        // p2c = unpack^T @ mlp_pm(h[:8400])
        launch_gemm(h,  pm_w1, pm_b1, t1, NNODES, DIM, FLAG_RELU, stream);
        launch_gemm(t1, pm_w2, pm_b2, t2, NNODES, DIM, FLAG_RELU, stream);
        launch_gemm(t2, pm_w3, pm_b3, t1, NNODES, DIM, 0, stream);
        gather_rows<<<NVARS, DIM, 0, stream>>>(t1, vidx, vcnt, VAR_CAP, msg);

        // (h,c) = LSTM_nu(p2c, h, c)  over all 12000 rows
        launch_gemm(msg, nu_wih, nullptr, gates, NVARS, 512, 0, stream);
        launch_gemm(h,   nu_whh, nullptr, gates, NVARS, 512, FLAG_ACCUM, stream);
        lstm_pw<<<(NVARS * DIM + 255) / 256, 256, 0, stream>>>(
            gates, (const float*)nu_bih, (const float*)nu_bhh, h, c, NVARS);
    }

    // vote = mlp_vv(h[8400:])[:, 0]
    launch_gemm(h + NNODES * DIM, vv_w1, vv_b1, t1, NLEAF, DIM, FLAG_RELU, stream);
    launch_gemm(t1, vv_w2, vv_b2, t2, NLEAF, DIM, FLAG_RELU, stream);
    vote_out<<<(NLEAF + 255) / 256, 256, 0, stream>>>(
        t2, (const float*)vv_w3, (const float*)vv_b3, (float*)d_out);
}